// Round 2
// baseline (833.403 us; speedup 1.0000x reference)
//
#include <hip/hip_runtime.h>
#include <stdint.h>

// NBMEHead: out[b,s,o] = sum_d avg[b,s,d] * W[o,d] + bias[o]
// avg = mean over 5 inverted-dropout passes, p = 0.1..0.5, JAX threefry PRNG
// (jax_threefry_partitionable=True scheme), root dropout key = key(42).
// VERIFIED bit-exact in R1 (absmax 0.0078 = fp reassociation noise only).
//
// R2 change: force v_alignbit_b32 for every threefry rotate via
// __builtin_amdgcn_alignbit. R1 measured ~750 VALU instrs/element vs ~390
// ideal at VALUBusy=102% -- hypothesis: rotate idiom lowered to shl+shr+or.

struct TF2 { uint32_t a, b; };

// ---- host-side constexpr threefry (for subkey precompute only) ----
__host__ __device__ constexpr uint32_t rotl_c(uint32_t x, int r) {
  return (x << r) | (x >> (32 - r));
}
__host__ __device__ constexpr TF2 tf2x32_c(uint32_t k0, uint32_t k1,
                                           uint32_t x0, uint32_t x1) {
  const uint32_t ks2 = k0 ^ k1 ^ 0x1BD11BDAu;
  x0 += k0; x1 += k1;
#define TFRC(r) { x0 += x1; x1 = rotl_c(x1, (r)); x1 ^= x0; }
  TFRC(13) TFRC(15) TFRC(26) TFRC(6)
  x0 += k1;  x1 += ks2 + 1u;
  TFRC(17) TFRC(29) TFRC(16) TFRC(24)
  x0 += ks2; x1 += k0 + 2u;
  TFRC(13) TFRC(15) TFRC(26) TFRC(6)
  x0 += k0;  x1 += k1 + 3u;
  TFRC(17) TFRC(29) TFRC(16) TFRC(24)
  x0 += k1;  x1 += ks2 + 4u;
  TFRC(13) TFRC(15) TFRC(26) TFRC(6)
  x0 += ks2; x1 += k0 + 5u;
#undef TFRC
  return TF2{x0, x1};
}

// Subkeys for the 5 dropout passes (fold-like split of key(42)).
constexpr TF2 SUBKEY[5] = {
  tf2x32_c(0u, 42u, 0u, 0u),
  tf2x32_c(0u, 42u, 0u, 1u),
  tf2x32_c(0u, 42u, 0u, 2u),
  tf2x32_c(0u, 42u, 0u, 3u),
  tf2x32_c(0u, 42u, 0u, 4u),
};

// keep iff bits < TS[j] (pre-shifted integer threshold; exact equivalence
// with JAX's float compare since u = (bits>>9)*2^-23 is exact).
__host__ __device__ constexpr uint32_t keep_threshold(double p) {
  float q = (float)(1.0 - p);
  double v = (double)q * 8388608.0;  // q * 2^23
  uint32_t t = (uint32_t)v;
  if ((double)t < v) ++t;            // ceil
  return t << 9;
}
constexpr uint32_t TS[5] = {
  keep_threshold(0.1), keep_threshold(0.2), keep_threshold(0.3),
  keep_threshold(0.4), keep_threshold(0.5),
};

// per-pass weight: (1/(1-p))/5 folded into one multiplier
__host__ __device__ constexpr float keep_weight(double p) {
  float q = (float)(1.0 - p);
  return (float)(1.0 / ((double)q * 5.0));
}
constexpr float WJ[5] = {
  keep_weight(0.1), keep_weight(0.2), keep_weight(0.3),
  keep_weight(0.4), keep_weight(0.5),
};

// ---- device threefry with guaranteed single-instruction rotates ----
// rotl(x, r) == rotr(x, 32-r) == v_alignbit_b32(x, x, 32-r); the shift
// amount 32-r is an inline constant (1..64 range -> free src2).
__device__ __forceinline__ uint32_t rotl_d(uint32_t x, int r) {
  return __builtin_amdgcn_alignbit(x, x, (uint32_t)(32 - r));
}

__device__ __forceinline__ uint32_t tf2x32_xor_d(uint32_t k0, uint32_t k1,
                                                 uint32_t i) {
  const uint32_t ks2 = k0 ^ k1 ^ 0x1BD11BDAu;   // compile-time constant
  uint32_t x0 = k0;          // counter hi word is 0
  uint32_t x1 = i + k1;
#define TFRD(r) { x0 += x1; x1 = rotl_d(x1, (r)); x1 ^= x0; }
  TFRD(13) TFRD(15) TFRD(26) TFRD(6)
  x0 += k1;  x1 += ks2 + 1u;
  TFRD(17) TFRD(29) TFRD(16) TFRD(24)
  x0 += ks2; x1 += k0 + 2u;
  TFRD(13) TFRD(15) TFRD(26) TFRD(6)
  x0 += k0;  x1 += k1 + 3u;
  TFRD(17) TFRD(29) TFRD(16) TFRD(24)
  x0 += k1;  x1 += ks2 + 4u;
  TFRD(13) TFRD(15) TFRD(26) TFRD(6)
  x0 += ks2; x1 += k0 + 5u;
#undef TFRD
  return x0 ^ x1;            // partitionable-mode 32-bit draw
}

// One block per (b,s) row of D=1024. 256 threads x 4 elements each.
// Grid = 32*2048 = 65536 blocks.
__global__ __launch_bounds__(256) void nbme_head_kernel(
    const float* __restrict__ x, const float* __restrict__ W,
    const float* __restrict__ bias, float* __restrict__ out) {
  const int row = blockIdx.x;          // b*2048 + s, in [0, 65536)
  const int tid = threadIdx.x;

  const uint32_t base = (uint32_t)row * 1024u + (uint32_t)(tid << 2);

  const float4 xv = ((const float4*)x)[row * 256 + tid];
  const float4 w0 = ((const float4*)(W))[tid];
  const float4 w1 = ((const float4*)(W + 1024))[tid];
  const float4 w2 = ((const float4*)(W + 2048))[tid];

  const float xs[4]  = {xv.x, xv.y, xv.z, xv.w};
  const float w0s[4] = {w0.x, w0.y, w0.z, w0.w};
  const float w1s[4] = {w1.x, w1.y, w1.z, w1.w};
  const float w2s[4] = {w2.x, w2.y, w2.z, w2.w};

  float acc0 = 0.f, acc1 = 0.f, acc2 = 0.f;

#pragma unroll
  for (int e = 0; e < 4; ++e) {
    const uint32_t i = base + (uint32_t)e;  // flat element index (< 2^26)
    float coef = 0.f;
#pragma unroll
    for (int j = 0; j < 5; ++j) {
      const uint32_t bits = tf2x32_xor_d(SUBKEY[j].a, SUBKEY[j].b, i);
      coef += (bits < TS[j]) ? WJ[j] : 0.f;
    }
    const float v = xs[e] * coef;           // avg[b,s,d]
    acc0 = fmaf(v, w0s[e], acc0);
    acc1 = fmaf(v, w1s[e], acc1);
    acc2 = fmaf(v, w2s[e], acc2);
  }

  // wave64 shuffle reduction of the three partial dots
#pragma unroll
  for (int off = 32; off > 0; off >>= 1) {
    acc0 += __shfl_down(acc0, off);
    acc1 += __shfl_down(acc1, off);
    acc2 += __shfl_down(acc2, off);
  }

  __shared__ float smem[4][3];
  const int lane = tid & 63, wave = tid >> 6;
  if (lane == 0) {
    smem[wave][0] = acc0; smem[wave][1] = acc1; smem[wave][2] = acc2;
  }
  __syncthreads();
  if (tid < 3) {
    float s = smem[0][tid] + smem[1][tid] + smem[2][tid] + smem[3][tid]
            + bias[tid];
    out[row * 3 + tid] = s;
  }
}

extern "C" void kernel_launch(void* const* d_in, const int* in_sizes, int n_in,
                              void* d_out, int out_size, void* d_ws,
                              size_t ws_size, hipStream_t stream) {
  const float* x    = (const float*)d_in[0];  // [32,2048,1024]
  const float* W    = (const float*)d_in[1];  // [3,1024]
  const float* bias = (const float*)d_in[2];  // [3]
  float* out        = (float*)d_out;          // [32,2048,3]

  nbme_head_kernel<<<dim3(65536), dim3(256), 0, stream>>>(x, W, bias, out);
}

// Round 3
// 832.996 us; speedup vs baseline: 1.0005x; 1.0005x over previous
//
#include <hip/hip_runtime.h>
#include <stdint.h>

// NBMEHead: out[b,s,o] = sum_d avg[b,s,d] * W[o,d] + bias[o]
// avg = mean over 5 inverted-dropout passes, p = 0.1..0.5, JAX threefry PRNG
// (jax_threefry_partitionable=True scheme), root dropout key = key(42).
// Bit-exact masks VERIFIED in R1/R2 (absmax 0.0078 = fp reassociation only).
//
// R3: instruction diet. (a) x0 key-injections folded into the next round's
// add as x0 = x0 + k + x1 (v_add3_u32, k in SGPR) -- 4 folds/threefry,
// 75 -> 71 VALU ops. (b) 8 elements/thread (128-thr block, 1 row/block)
// halves per-wave fixed overhead. Kernel is VALU-issue-bound (VALUBusy~100%,
// HBM 2.6%), so dur should track instruction count: predict ~600 us.

struct TF2 { uint32_t a, b; };

// ---- host-side constexpr threefry (subkey precompute only) ----
__host__ __device__ constexpr uint32_t rotl_c(uint32_t x, int r) {
  return (x << r) | (x >> (32 - r));
}
__host__ __device__ constexpr TF2 tf2x32_c(uint32_t k0, uint32_t k1,
                                           uint32_t x0, uint32_t x1) {
  const uint32_t ks2 = k0 ^ k1 ^ 0x1BD11BDAu;
  x0 += k0; x1 += k1;
#define TFRC(r) { x0 += x1; x1 = rotl_c(x1, (r)); x1 ^= x0; }
  TFRC(13) TFRC(15) TFRC(26) TFRC(6)
  x0 += k1;  x1 += ks2 + 1u;
  TFRC(17) TFRC(29) TFRC(16) TFRC(24)
  x0 += ks2; x1 += k0 + 2u;
  TFRC(13) TFRC(15) TFRC(26) TFRC(6)
  x0 += k0;  x1 += k1 + 3u;
  TFRC(17) TFRC(29) TFRC(16) TFRC(24)
  x0 += k1;  x1 += ks2 + 4u;
  TFRC(13) TFRC(15) TFRC(26) TFRC(6)
  x0 += ks2; x1 += k0 + 5u;
#undef TFRC
  return TF2{x0, x1};
}

constexpr TF2 SUBKEY[5] = {
  tf2x32_c(0u, 42u, 0u, 0u),
  tf2x32_c(0u, 42u, 0u, 1u),
  tf2x32_c(0u, 42u, 0u, 2u),
  tf2x32_c(0u, 42u, 0u, 3u),
  tf2x32_c(0u, 42u, 0u, 4u),
};

// keep iff bits < TS[j] (pre-shifted integer threshold; exact equivalence
// with JAX's float compare since u = (bits>>9)*2^-23 is exact).
__host__ __device__ constexpr uint32_t keep_threshold(double p) {
  float q = (float)(1.0 - p);
  double v = (double)q * 8388608.0;  // q * 2^23
  uint32_t t = (uint32_t)v;
  if ((double)t < v) ++t;            // ceil
  return t << 9;
}
constexpr uint32_t TS[5] = {
  keep_threshold(0.1), keep_threshold(0.2), keep_threshold(0.3),
  keep_threshold(0.4), keep_threshold(0.5),
};

__host__ __device__ constexpr float keep_weight(double p) {
  float q = (float)(1.0 - p);
  return (float)(1.0 / ((double)q * 5.0));
}
constexpr float WJ[5] = {
  keep_weight(0.1), keep_weight(0.2), keep_weight(0.3),
  keep_weight(0.4), keep_weight(0.5),
};

// rotl(x, r) == rotr(x, 32-r) == v_alignbit_b32(x, x, 32-r)
__device__ __forceinline__ uint32_t rotl_d(uint32_t x, int r) {
  return __builtin_amdgcn_alignbit(x, x, (uint32_t)(32 - r));
}

// Threefry-2x32 with x0-injections folded into the following round's add
// (exact: wraparound addition is associative). 71 VALU ops if add3 forms.
__device__ __forceinline__ uint32_t tf2x32_xor_d(uint32_t k0, uint32_t k1,
                                                 uint32_t i) {
  const uint32_t ks2 = k0 ^ k1 ^ 0x1BD11BDAu;
  uint32_t x1 = i + k1;
  uint32_t x0 = x1 + k0;                       // init + round-1 add folded
  x1 = rotl_d(x1, 13); x1 ^= x0;
#define TFR3(r) { x0 += x1; x1 = rotl_d(x1, (r)); x1 ^= x0; }
  TFR3(15) TFR3(26) TFR3(6)                    // r2..r4
  x1 += ks2 + 1u;
  x0 = x0 + k1 + x1;                           // inj1 + r5 add (v_add3)
  x1 = rotl_d(x1, 17); x1 ^= x0;
  TFR3(29) TFR3(16) TFR3(24)                   // r6..r8
  x1 += k0 + 2u;
  x0 = x0 + ks2 + x1;                          // inj2 + r9 add
  x1 = rotl_d(x1, 13); x1 ^= x0;
  TFR3(15) TFR3(26) TFR3(6)                    // r10..r12
  x1 += k1 + 3u;
  x0 = x0 + k0 + x1;                           // inj3 + r13 add
  x1 = rotl_d(x1, 17); x1 ^= x0;
  TFR3(29) TFR3(16) TFR3(24)                   // r14..r16
  x1 += ks2 + 4u;
  x0 = x0 + k1 + x1;                           // inj4 + r17 add
  x1 = rotl_d(x1, 13); x1 ^= x0;
  TFR3(15) TFR3(26) TFR3(6)                    // r18..r20
#undef TFR3
  return (x0 + ks2) ^ (x1 + k0 + 5u);          // final injection + output xor
}

// One block (128 threads = 2 waves) per (b,s) row. 8 elements/thread.
// Grid = 32*2048 = 65536 blocks.
__global__ __launch_bounds__(128) void nbme_head_kernel(
    const float* __restrict__ x, const float* __restrict__ W,
    const float* __restrict__ bias, float* __restrict__ out) {
  const int row = blockIdx.x;          // b*2048 + s, in [0, 65536)
  const int tid = threadIdx.x;         // [0, 128)

  const uint32_t base = (uint32_t)row * 1024u + (uint32_t)(tid << 3);

  // 8 x-values and 3x8 W-values per thread, as float4 pairs
  const float4* xp = (const float4*)(x + (size_t)row * 1024 + (tid << 3));
  const float4 xa = xp[0], xb = xp[1];
  const float4* w0p = (const float4*)(W + (tid << 3));
  const float4* w1p = (const float4*)(W + 1024 + (tid << 3));
  const float4* w2p = (const float4*)(W + 2048 + (tid << 3));
  const float4 w0a = w0p[0], w0b = w0p[1];
  const float4 w1a = w1p[0], w1b = w1p[1];
  const float4 w2a = w2p[0], w2b = w2p[1];

  const float xs[8]  = {xa.x, xa.y, xa.z, xa.w, xb.x, xb.y, xb.z, xb.w};
  const float w0s[8] = {w0a.x, w0a.y, w0a.z, w0a.w, w0b.x, w0b.y, w0b.z, w0b.w};
  const float w1s[8] = {w1a.x, w1a.y, w1a.z, w1a.w, w1b.x, w1b.y, w1b.z, w1b.w};
  const float w2s[8] = {w2a.x, w2a.y, w2a.z, w2a.w, w2b.x, w2b.y, w2b.z, w2b.w};

  float acc0 = 0.f, acc1 = 0.f, acc2 = 0.f;

#pragma unroll
  for (int e = 0; e < 8; ++e) {
    const uint32_t i = base + (uint32_t)e;  // flat element index (< 2^26)
    float coef = 0.f;
#pragma unroll
    for (int j = 0; j < 5; ++j) {
      const uint32_t bits = tf2x32_xor_d(SUBKEY[j].a, SUBKEY[j].b, i);
      coef += (bits < TS[j]) ? WJ[j] : 0.f;
    }
    const float v = xs[e] * coef;           // avg[b,s,d]
    acc0 = fmaf(v, w0s[e], acc0);
    acc1 = fmaf(v, w1s[e], acc1);
    acc2 = fmaf(v, w2s[e], acc2);
  }

  // wave64 shuffle reduction of the three partial dots
#pragma unroll
  for (int off = 32; off > 0; off >>= 1) {
    acc0 += __shfl_down(acc0, off);
    acc1 += __shfl_down(acc1, off);
    acc2 += __shfl_down(acc2, off);
  }

  __shared__ float smem[2][3];
  const int lane = tid & 63, wave = tid >> 6;
  if (lane == 0) {
    smem[wave][0] = acc0; smem[wave][1] = acc1; smem[wave][2] = acc2;
  }
  __syncthreads();
  if (tid < 3) {
    out[row * 3 + tid] = smem[0][tid] + smem[1][tid] + bias[tid];
  }
}

extern "C" void kernel_launch(void* const* d_in, const int* in_sizes, int n_in,
                              void* d_out, int out_size, void* d_ws,
                              size_t ws_size, hipStream_t stream) {
  const float* x    = (const float*)d_in[0];  // [32,2048,1024]
  const float* W    = (const float*)d_in[1];  // [3,1024]
  const float* bias = (const float*)d_in[2];  // [3]
  float* out        = (float*)d_out;          // [32,2048,3]

  nbme_head_kernel<<<dim3(65536), dim3(128), 0, stream>>>(x, W, bias, out);
}